// Round 3
// baseline (91.486 us; speedup 1.0000x reference)
//
#include <hip/hip_runtime.h>
#include <math.h>

// Problem constants (from reference):
//   B=4, N=1024 -> 4096 atoms; IN_CH=OUT_CH=16; N_BASIS=16; N_FEAT=19
//   centers = linspace(0,3.5,16) -> c_f = f*(3.5/15); GAMMA = 3.5/16
//   out /= sqrt(24)
#define IN_CH 16
#define OUT_CH 16
#define N_BASIS 16
#define N_FEAT 19
#define YF 20                         // padded feature stride (19 + 1 pad)
#define Y_STRIDE (OUT_CH * YF)        // 320 floats per atom, layout y[a][o][f]
#define GAMMA_INV (16.0f / 3.5f)
#define CENTER_STEP (3.5f / 15.0f)
#define INV_SQRT_NNORM 0.20412414523193154f  // 1/sqrt(24)
#define EPB 64                        // edges per block in edge kernel

// ---------------------------------------------------------------------------
// Kernel A: y[a, o, f] = sum_i W[f,o,i] * x[a,i]   (note transposed layout,
// padded to 20 features so the edge kernel can gather 5 float4 per lane).
// One block per atom, 320 threads: t -> (o = t/20, f = t%20). Fully coalesced
// y writes. Also zeroes this atom's out slice (harness poisons d_out).
// ---------------------------------------------------------------------------
__global__ __launch_bounds__(320) void precompute_y(
    const float* __restrict__ x, const float* __restrict__ W,
    float* __restrict__ y, float* __restrict__ out) {
  __shared__ float xs[IN_CH];
  const int a = blockIdx.x;
  const int t = threadIdx.x;
  if (t < IN_CH) {
    xs[t] = x[a * IN_CH + t];
    out[a * OUT_CH + t] = 0.0f;
  }
  __syncthreads();
  const int o = t / YF;
  const int f = t % YF;
  float acc = 0.f;
  if (f < N_FEAT) {
    const float4* w4 = (const float4*)(W + (f * OUT_CH + o) * IN_CH);
#pragma unroll
    for (int q = 0; q < 4; ++q) {
      float4 w = w4[q];
      acc += w.x * xs[4 * q + 0] + w.y * xs[4 * q + 1] +
             w.z * xs[4 * q + 2] + w.w * xs[4 * q + 3];
    }
  }
  y[(size_t)a * Y_STRIDE + t] = acc;  // pad slot written as 0
}

// ---------------------------------------------------------------------------
// Kernel B: per-edge msg[e,o] = sum_f feat[e,f] * y[src_e, o, f], scattered
// to out[dst]. 64 edges per 256-thread block; thread (g = t/16, o = t&15)
// handles edge slots s = g + 16j, j=0..3. Edge data staged coalesced in LDS.
// y gather: 5 float4 loads per (slot, lane). Adjacent same-dst runs (edge
// list is dst-sorted within each periodic-shift chunk) are merged in LDS;
// only run tails emit a global fp32 atomicAdd.
// ---------------------------------------------------------------------------
__global__ __launch_bounds__(256) void edge_scatter(
    const float* __restrict__ y, const float* __restrict__ edge_vec,
    const int* __restrict__ edge_src, const int* __restrict__ edge_dst,
    float* __restrict__ out, int E) {
  __shared__ float ev[EPB * 3];
  __shared__ int srcs[EPB];
  __shared__ int dsts[EPB];
  __shared__ float feat[EPB][YF];
  __shared__ float msg[EPB][OUT_CH];

  const int t = threadIdx.x;
  const int e0 = blockIdx.x * EPB;

  // ---- stage edge data (coalesced) ----
  if (t < EPB * 3) {
    const int idx = e0 * 3 + t;
    ev[t] = (idx < E * 3) ? edge_vec[idx] : 0.0f;
  }
  if (t < EPB) {
    srcs[t] = (e0 + t < E) ? edge_src[e0 + t] : 0;
  } else if (t < 2 * EPB) {
    const int s = t - EPB;
    dsts[s] = (e0 + s < E) ? edge_dst[e0 + s] : (-1 - s);  // unique sentinel
  }
  __syncthreads();

  const int g = t >> 4;   // 0..15
  const int o = t & 15;   // channel / basis index

  // ---- per-slot features ----
#pragma unroll
  for (int j = 0; j < 4; ++j) {
    const int s = g + 16 * j;
    const float vx = ev[3 * s + 0], vy = ev[3 * s + 1], vz = ev[3 * s + 2];
    const float r = sqrtf(vx * vx + vy * vy + vz * vz);
    const float tt = (r - CENTER_STEP * (float)o) * GAMMA_INV;
    feat[s][o] = __expf(-tt * tt);
    if (o < 3) {
      const float inv = (r > 1e-10f) ? (1.0f / r) : 0.0f;
      const float comp = (o == 0) ? vx : ((o == 1) ? vy : vz);
      feat[s][N_BASIS + o] = comp * inv;
    }
    if (o == 3) feat[s][N_FEAT] = 0.0f;  // pad slot
  }
  __syncthreads();

  // ---- per-slot message: dot(feat[s][0:19], y[src, o, 0:19]) ----
#pragma unroll
  for (int j = 0; j < 4; ++j) {
    const int s = g + 16 * j;
    float acc = 0.f;
    if (e0 + s < E) {
      const float4* yr = (const float4*)(y + ((size_t)srcs[s] * OUT_CH + o) * YF);
      const float4* fr = (const float4*)(&feat[s][0]);
#pragma unroll
      for (int q = 0; q < 5; ++q) {
        float4 yv = yr[q];
        float4 fv = fr[q];
        acc += yv.x * fv.x + yv.y * fv.y + yv.z * fv.z + yv.w * fv.w;
      }
      // pad element contributes feat=0 * y=0 -> exact
    }
    msg[s][o] = acc;
  }
  __syncthreads();

  // ---- run-tail dedup + atomic emit ----
#pragma unroll
  for (int j = 0; j < 4; ++j) {
    const int s = g + 16 * j;
    const int d = dsts[s];
    const bool tail = (s == EPB - 1) || (dsts[s + 1] != d);
    if (tail && d >= 0) {
      float tot = 0.f;
      int q = s;
      while (q >= 0 && dsts[q] == d) { tot += msg[q][o]; --q; }
      atomicAdd(&out[d * OUT_CH + o], tot * INV_SQRT_NNORM);
    }
  }
}

// ---------------------------------------------------------------------------
// Fallback (only if ws too small for y): direct per-edge evaluation.
// ---------------------------------------------------------------------------
__global__ __launch_bounds__(256) void edge_direct(
    const float* __restrict__ x, const float* __restrict__ W,
    const float* __restrict__ edge_vec, const int* __restrict__ edge_src,
    const int* __restrict__ edge_dst, float* __restrict__ out, int E) {
  __shared__ float Ws[N_FEAT * OUT_CH * IN_CH];
  __shared__ float feat[16][N_FEAT];
  __shared__ float xs[16][IN_CH];

  const int t = threadIdx.x;
  for (int i = t; i < N_FEAT * OUT_CH * IN_CH; i += 256) Ws[i] = W[i];

  const int eg = t >> 4;
  const int o = t & 15;
  const int e = blockIdx.x * 16 + eg;
  const bool valid = (e < E);

  float vx = 0.f, vy = 0.f, vz = 0.f;
  int src = 0, dst = 0;
  if (valid) {
    vx = edge_vec[3 * e + 0];
    vy = edge_vec[3 * e + 1];
    vz = edge_vec[3 * e + 2];
    src = edge_src[e];
    dst = edge_dst[e];
    xs[eg][o] = x[src * IN_CH + o];
  }
  const float r = sqrtf(vx * vx + vy * vy + vz * vz);
  const float tt = (r - CENTER_STEP * (float)o) * GAMMA_INV;
  feat[eg][o] = __expf(-tt * tt);
  if (o < 3) {
    const float inv = (r > 1e-10f) ? (1.0f / r) : 0.0f;
    const float comp = (o == 0) ? vx : ((o == 1) ? vy : vz);
    feat[eg][N_BASIS + o] = comp * inv;
  }
  __syncthreads();

  if (valid) {
    float acc = 0.f;
#pragma unroll
    for (int f = 0; f < N_FEAT; ++f) {
      const float* wrow = &Ws[(f * OUT_CH + o) * IN_CH];
      float dot = 0.f;
#pragma unroll
      for (int i = 0; i < IN_CH; ++i) dot += wrow[i] * xs[eg][i];
      acc += feat[eg][f] * dot;
    }
    atomicAdd(&out[dst * OUT_CH + o], acc * INV_SQRT_NNORM);
  }
}

extern "C" void kernel_launch(void* const* d_in, const int* in_sizes, int n_in,
                              void* d_out, int out_size, void* d_ws,
                              size_t ws_size, hipStream_t stream) {
  const float* x = (const float*)d_in[0];        // [n_atoms, 16]
  const float* W = (const float*)d_in[1];        // [19, 16, 16]
  const float* edge_vec = (const float*)d_in[2]; // [E, 3]
  const int* edge_src = (const int*)d_in[3];     // [E]
  const int* edge_dst = (const int*)d_in[4];     // [E]
  float* out = (float*)d_out;

  const int E = in_sizes[3];
  const int n_atoms = in_sizes[0] / IN_CH;

  const size_t y_bytes = (size_t)n_atoms * Y_STRIDE * sizeof(float);
  if (ws_size >= y_bytes) {
    float* y = (float*)d_ws;
    precompute_y<<<n_atoms, 320, 0, stream>>>(x, W, y, out);
    edge_scatter<<<(E + EPB - 1) / EPB, 256, 0, stream>>>(y, edge_vec, edge_src,
                                                          edge_dst, out, E);
  } else {
    hipMemsetAsync(out, 0, (size_t)out_size * sizeof(float), stream);
    edge_direct<<<(E + 15) / 16, 256, 0, stream>>>(x, W, edge_vec, edge_src,
                                                   edge_dst, out, E);
  }
}

// Round 4
// 90.824 us; speedup vs baseline: 1.0073x; 1.0073x over previous
//
#include <hip/hip_runtime.h>
#include <math.h>

// Problem constants (from reference):
//   B=4, N=1024 -> 4096 atoms; IN_CH=OUT_CH=16; N_BASIS=16; N_FEAT=19
//   centers = linspace(0,3.5,16) -> c_f = f*(3.5/15); GAMMA = 3.5/16
//   out /= sqrt(24)
#define IN_CH 16
#define OUT_CH 16
#define N_BASIS 16
#define N_FEAT 19
#define YF 20                         // padded feature stride (19 + 1 pad)
#define Y_STRIDE (OUT_CH * YF)        // 320 floats per atom, layout y[a][o][f]
#define GAMMA_INV (16.0f / 3.5f)
#define CENTER_STEP (3.5f / 15.0f)
#define INV_SQRT_NNORM 0.20412414523193154f  // 1/sqrt(24)
#define EPB 32                        // edges per block (two 16-edge windows)

// ---------------------------------------------------------------------------
// Kernel A: y[a, o, f] = sum_i W[f,o,i] * x[a,i]  (transposed, padded layout
// so the edge kernel gathers 5 contiguous float4 per lane). One block/atom,
// 320 threads: t -> (o = t/20, f = t%20); coalesced y writes. Also zeroes
// this atom's out slice (harness poisons d_out before every timed launch).
// ---------------------------------------------------------------------------
__global__ __launch_bounds__(320) void precompute_y(
    const float* __restrict__ x, const float* __restrict__ W,
    float* __restrict__ y, float* __restrict__ out) {
  __shared__ float xs[IN_CH];
  const int a = blockIdx.x;
  const int t = threadIdx.x;
  if (t < IN_CH) {
    xs[t] = x[a * IN_CH + t];
    out[a * OUT_CH + t] = 0.0f;
  }
  __syncthreads();
  const int o = t / YF;
  const int f = t % YF;
  float acc = 0.f;
  if (f < N_FEAT) {
    const float4* w4 = (const float4*)(W + (f * OUT_CH + o) * IN_CH);
#pragma unroll
    for (int q = 0; q < 4; ++q) {
      float4 w = w4[q];
      acc += w.x * xs[4 * q + 0] + w.y * xs[4 * q + 1] +
             w.z * xs[4 * q + 2] + w.w * xs[4 * q + 3];
    }
  }
  y[(size_t)a * Y_STRIDE + t] = acc;  // pad slot written as 0
}

// ---------------------------------------------------------------------------
// Kernel B: msg[e,o] = sum_f feat[e,f] * y[src_e, o, f] -> atomicAdd out[dst].
// 32 edges / 256-thread block; thread (g = t>>4, o = t&15) owns slots g and
// g+16 (two independent load chains per thread = ILP). Dedup: R2's fixed
// fully-unrolled 16-slot window scan, independently per window — no serial
// data-dependent walks. Edge data staged coalesced in LDS.
// ---------------------------------------------------------------------------
__global__ __launch_bounds__(256) void edge_scatter(
    const float* __restrict__ y, const float* __restrict__ edge_vec,
    const int* __restrict__ edge_src, const int* __restrict__ edge_dst,
    float* __restrict__ out, int E) {
  __shared__ float ev[EPB * 3];
  __shared__ int srcs[EPB];
  __shared__ int dsts[EPB];
  __shared__ float feat[EPB][YF];
  __shared__ float msg[EPB][OUT_CH];

  const int t = threadIdx.x;
  const int e0 = blockIdx.x * EPB;

  // ---- stage edge data (coalesced) ----
  if (t < EPB * 3) {
    const int idx = e0 * 3 + t;
    ev[t] = (idx < E * 3) ? edge_vec[idx] : 0.0f;
  } else if (t < EPB * 3 + EPB) {
    const int s = t - EPB * 3;
    srcs[s] = (e0 + s < E) ? edge_src[e0 + s] : 0;
  } else if (t < EPB * 3 + 2 * EPB) {
    const int s = t - (EPB * 3 + EPB);
    dsts[s] = (e0 + s < E) ? edge_dst[e0 + s] : (-1 - s);  // unique sentinel
  }
  __syncthreads();

  const int g = t >> 4;   // 0..15
  const int o = t & 15;   // channel / basis index

  // ---- per-slot features ----
#pragma unroll
  for (int j = 0; j < 2; ++j) {
    const int s = g + 16 * j;
    const float vx = ev[3 * s + 0], vy = ev[3 * s + 1], vz = ev[3 * s + 2];
    const float r = sqrtf(vx * vx + vy * vy + vz * vz);
    const float tt = (r - CENTER_STEP * (float)o) * GAMMA_INV;
    feat[s][o] = __expf(-tt * tt);
    if (o < 3) {
      // reference: rhat = where(r > 1e-10, vec / max(r,1e-10), 0)
      const float inv = (r > 1e-10f) ? (1.0f / r) : 0.0f;
      const float comp = (o == 0) ? vx : ((o == 1) ? vy : vz);
      feat[s][N_BASIS + o] = comp * inv;
    }
    if (o == 3) feat[s][N_FEAT] = 0.0f;  // pad slot
  }
  __syncthreads();

  // ---- per-slot message: dot(feat[s][0:20], y[src, o, 0:20]) ----
#pragma unroll
  for (int j = 0; j < 2; ++j) {
    const int s = g + 16 * j;
    float acc = 0.f;
    if (e0 + s < E) {
      const float4* yr = (const float4*)(y + ((size_t)srcs[s] * OUT_CH + o) * YF);
      const float4* fr = (const float4*)(&feat[s][0]);
#pragma unroll
      for (int q = 0; q < 5; ++q) {
        float4 yv = yr[q];
        float4 fv = fr[q];
        acc += yv.x * fv.x + yv.y * fv.y + yv.z * fv.z + yv.w * fv.w;
      }
      // pad element: feat=0 * y=0 -> exact
    }
    msg[s][o] = acc;
  }
  __syncthreads();

  // ---- fixed-window dedup (unrolled, no serial walks) + atomic emit ----
#pragma unroll
  for (int j = 0; j < 2; ++j) {
    const int base = 16 * j;
    const int s = base + g;
    const int mydst = dsts[s];
    int leader = g;
#pragma unroll
    for (int k = 0; k < 16; ++k) {
      if (dsts[base + k] == mydst) { leader = k; break; }
    }
    if (leader == g && mydst >= 0) {
      float total = 0.f;
#pragma unroll
      for (int k = 0; k < 16; ++k) {
        if (k >= g && dsts[base + k] == mydst) total += msg[base + k][o];
      }
      atomicAdd(&out[mydst * OUT_CH + o], total * INV_SQRT_NNORM);
    }
  }
}

// ---------------------------------------------------------------------------
// Fallback (only if ws too small for y): direct per-edge evaluation.
// ---------------------------------------------------------------------------
__global__ __launch_bounds__(256) void edge_direct(
    const float* __restrict__ x, const float* __restrict__ W,
    const float* __restrict__ edge_vec, const int* __restrict__ edge_src,
    const int* __restrict__ edge_dst, float* __restrict__ out, int E) {
  __shared__ float Ws[N_FEAT * OUT_CH * IN_CH];
  __shared__ float feat[16][N_FEAT];
  __shared__ float xs[16][IN_CH];

  const int t = threadIdx.x;
  for (int i = t; i < N_FEAT * OUT_CH * IN_CH; i += 256) Ws[i] = W[i];

  const int eg = t >> 4;
  const int o = t & 15;
  const int e = blockIdx.x * 16 + eg;
  const bool valid = (e < E);

  float vx = 0.f, vy = 0.f, vz = 0.f;
  int src = 0, dst = 0;
  if (valid) {
    vx = edge_vec[3 * e + 0];
    vy = edge_vec[3 * e + 1];
    vz = edge_vec[3 * e + 2];
    src = edge_src[e];
    dst = edge_dst[e];
    xs[eg][o] = x[src * IN_CH + o];
  }
  const float r = sqrtf(vx * vx + vy * vy + vz * vz);
  const float tt = (r - CENTER_STEP * (float)o) * GAMMA_INV;
  feat[eg][o] = __expf(-tt * tt);
  if (o < 3) {
    const float inv = (r > 1e-10f) ? (1.0f / r) : 0.0f;
    const float comp = (o == 0) ? vx : ((o == 1) ? vy : vz);
    feat[eg][N_BASIS + o] = comp * inv;
  }
  __syncthreads();

  if (valid) {
    float acc = 0.f;
#pragma unroll
    for (int f = 0; f < N_FEAT; ++f) {
      const float* wrow = &Ws[(f * OUT_CH + o) * IN_CH];
      float dot = 0.f;
#pragma unroll
      for (int i = 0; i < IN_CH; ++i) dot += wrow[i] * xs[eg][i];
      acc += feat[eg][f] * dot;
    }
    atomicAdd(&out[dst * OUT_CH + o], acc * INV_SQRT_NNORM);
  }
}

extern "C" void kernel_launch(void* const* d_in, const int* in_sizes, int n_in,
                              void* d_out, int out_size, void* d_ws,
                              size_t ws_size, hipStream_t stream) {
  const float* x = (const float*)d_in[0];        // [n_atoms, 16]
  const float* W = (const float*)d_in[1];        // [19, 16, 16]
  const float* edge_vec = (const float*)d_in[2]; // [E, 3]
  const int* edge_src = (const int*)d_in[3];     // [E]
  const int* edge_dst = (const int*)d_in[4];     // [E]
  float* out = (float*)d_out;

  const int E = in_sizes[3];
  const int n_atoms = in_sizes[0] / IN_CH;

  const size_t y_bytes = (size_t)n_atoms * Y_STRIDE * sizeof(float);
  if (ws_size >= y_bytes) {
    float* y = (float*)d_ws;
    precompute_y<<<n_atoms, 320, 0, stream>>>(x, W, y, out);
    edge_scatter<<<(E + EPB - 1) / EPB, 256, 0, stream>>>(y, edge_vec, edge_src,
                                                          edge_dst, out, E);
  } else {
    hipMemsetAsync(out, 0, (size_t)out_size * sizeof(float), stream);
    edge_direct<<<(E + 15) / 16, 256, 0, stream>>>(x, W, edge_vec, edge_src,
                                                   edge_dst, out, E);
  }
}

// Round 5
// 81.278 us; speedup vs baseline: 1.1256x; 1.1174x over previous
//
#include <hip/hip_runtime.h>
#include <hip/hip_fp16.h>
#include <math.h>

// Problem constants (from reference):
//   B=4, N=1024 -> 4096 atoms; IN_CH=OUT_CH=16; N_BASIS=16; N_FEAT=19
//   centers = linspace(0,3.5,16) -> c_f = f*(3.5/15); GAMMA = 3.5/16
//   out /= sqrt(24)
#define IN_CH 16
#define OUT_CH 16
#define N_BASIS 16
#define N_FEAT 19                    // 16 basis + 3 rhat
#define Y_STRIDE (N_FEAT * OUT_CH)   // 304 halfs per atom, layout y[a][f][o]
#define GAMMA_INV (16.0f / 3.5f)
#define CENTER_STEP (3.5f / 15.0f)
#define INV_SQRT_NNORM 0.20412414523193154f  // 1/sqrt(24), folded into y

// ---------------------------------------------------------------------------
// Kernel A: y[a, f, o] = (1/sqrt(24)) * sum_i W[f,o,i] * x[a,i], stored fp16.
// Layout [a][f][o]: a 16-lane edge-group in kernel B reads 16 contiguous
// halfs (32 B) per feature -> coalesced quarter-wave loads. y = 2.43 MB,
// resident in each XCD's 4 MiB L2. One block/atom; t -> (f=t/16, o=t%16);
// W row W[f,o,:] contiguous float4s. Also zeroes this atom's out slice
// (harness poisons d_out before every timed launch).
// ---------------------------------------------------------------------------
__global__ __launch_bounds__(320) void precompute_y(
    const float* __restrict__ x, const float* __restrict__ W,
    __half* __restrict__ y, float* __restrict__ out) {
  __shared__ float xs[IN_CH];
  const int a = blockIdx.x;
  const int t = threadIdx.x;
  if (t < IN_CH) {
    xs[t] = x[a * IN_CH + t];
    out[a * OUT_CH + t] = 0.0f;
  }
  __syncthreads();
  if (t < Y_STRIDE) {
    const float4* w4 = (const float4*)(W + t * IN_CH);
    float acc = 0.f;
#pragma unroll
    for (int q = 0; q < 4; ++q) {
      float4 w = w4[q];
      acc += w.x * xs[4 * q + 0] + w.y * xs[4 * q + 1] +
             w.z * xs[4 * q + 2] + w.w * xs[4 * q + 3];
    }
    // fold 1/sqrt(24) here (before fp16 rounding: ~5x smaller abs error)
    y[(size_t)a * Y_STRIDE + t] = __float2half(acc * INV_SQRT_NNORM);
  }
}

// ---------------------------------------------------------------------------
// Kernel B (R2 structure): msg[e,o] = sum_f feat[e,f] * y[src_e, f, o],
// scattered to out[dst]. 16 lanes per edge, 16 edges per 256-thread block.
// One __expf per lane; features shared via LDS. y gather: 19 coalesced
// 32-B quarter-wave half loads. Fixed fully-unrolled 16-slot window dedup
// (edge list is dst-sorted within each periodic-shift chunk) -> only unique
// (dst, channel) pairs issue a global fp32 atomicAdd.
// ---------------------------------------------------------------------------
__global__ __launch_bounds__(256) void edge_scatter(
    const __half* __restrict__ y, const float* __restrict__ edge_vec,
    const int* __restrict__ edge_src, const int* __restrict__ edge_dst,
    float* __restrict__ out, int E) {
  __shared__ float feat[16][N_FEAT];
  __shared__ float msg[16][OUT_CH];
  __shared__ int dsts[16];

  const int t = threadIdx.x;
  const int eg = t >> 4;   // edge slot within block, 0..15
  const int o = t & 15;    // output channel / basis index
  const int e = blockIdx.x * 16 + eg;
  const bool valid = (e < E);

  float vx = 0.f, vy = 0.f, vz = 0.f;
  int src = 0;
  if (valid) {
    vx = edge_vec[3 * e + 0];
    vy = edge_vec[3 * e + 1];
    vz = edge_vec[3 * e + 2];
    src = edge_src[e];
    if (o == 0) dsts[eg] = edge_dst[e];
  } else if (o == 0) {
    dsts[eg] = -1 - eg;  // unique sentinel: never merged, never emitted
  }
  const float r = sqrtf(vx * vx + vy * vy + vz * vz);

  // basis feature o: exp(-((r - c_o)/gamma)^2)
  const float tt = (r - CENTER_STEP * (float)o) * GAMMA_INV;
  feat[eg][o] = __expf(-tt * tt);
  if (o < 3) {
    // reference: rhat = where(r > 1e-10, vec / max(r,1e-10), 0)
    const float inv = (r > 1e-10f) ? (1.0f / r) : 0.0f;
    const float comp = (o == 0) ? vx : ((o == 1) ? vy : vz);
    feat[eg][N_BASIS + o] = comp * inv;
  }
  __syncthreads();

  float acc = 0.f;
  if (valid) {
    const __half* __restrict__ yrow = y + (size_t)src * Y_STRIDE + o;
#pragma unroll
    for (int f = 0; f < N_FEAT; ++f)
      acc += feat[eg][f] * __half2float(yrow[f * OUT_CH]);
  }
  msg[eg][o] = acc;  // 0 for invalid slots
  __syncthreads();

  // Per-block dst dedup: first slot with a given dst emits the merged sum.
  const int mydst = dsts[eg];
  int leader = eg;
#pragma unroll
  for (int j = 0; j < 16; ++j) {
    if (dsts[j] == mydst) { leader = j; break; }
  }
  if (leader == eg && mydst >= 0) {
    float total = 0.f;
#pragma unroll
    for (int j = 0; j < 16; ++j) {
      if (j >= eg && dsts[j] == mydst) total += msg[j][o];
    }
    atomicAdd(&out[mydst * OUT_CH + o], total);  // 1/sqrt(24) already in y
  }
}

// ---------------------------------------------------------------------------
// Fallback (only if ws too small for y): direct per-edge evaluation.
// ---------------------------------------------------------------------------
__global__ __launch_bounds__(256) void edge_direct(
    const float* __restrict__ x, const float* __restrict__ W,
    const float* __restrict__ edge_vec, const int* __restrict__ edge_src,
    const int* __restrict__ edge_dst, float* __restrict__ out, int E) {
  __shared__ float Ws[N_FEAT * OUT_CH * IN_CH];
  __shared__ float feat[16][N_FEAT];
  __shared__ float xs[16][IN_CH];

  const int t = threadIdx.x;
  for (int i = t; i < N_FEAT * OUT_CH * IN_CH; i += 256) Ws[i] = W[i];

  const int eg = t >> 4;
  const int o = t & 15;
  const int e = blockIdx.x * 16 + eg;
  const bool valid = (e < E);

  float vx = 0.f, vy = 0.f, vz = 0.f;
  int src = 0, dst = 0;
  if (valid) {
    vx = edge_vec[3 * e + 0];
    vy = edge_vec[3 * e + 1];
    vz = edge_vec[3 * e + 2];
    src = edge_src[e];
    dst = edge_dst[e];
    xs[eg][o] = x[src * IN_CH + o];
  }
  const float r = sqrtf(vx * vx + vy * vy + vz * vz);
  const float tt = (r - CENTER_STEP * (float)o) * GAMMA_INV;
  feat[eg][o] = __expf(-tt * tt);
  if (o < 3) {
    const float inv = (r > 1e-10f) ? (1.0f / r) : 0.0f;
    const float comp = (o == 0) ? vx : ((o == 1) ? vy : vz);
    feat[eg][N_BASIS + o] = comp * inv;
  }
  __syncthreads();

  if (valid) {
    float acc = 0.f;
#pragma unroll
    for (int f = 0; f < N_FEAT; ++f) {
      const float* wrow = &Ws[(f * OUT_CH + o) * IN_CH];
      float dot = 0.f;
#pragma unroll
      for (int i = 0; i < IN_CH; ++i) dot += wrow[i] * xs[eg][i];
      acc += feat[eg][f] * dot;
    }
    atomicAdd(&out[dst * OUT_CH + o], acc * INV_SQRT_NNORM);
  }
}

extern "C" void kernel_launch(void* const* d_in, const int* in_sizes, int n_in,
                              void* d_out, int out_size, void* d_ws,
                              size_t ws_size, hipStream_t stream) {
  const float* x = (const float*)d_in[0];        // [n_atoms, 16]
  const float* W = (const float*)d_in[1];        // [19, 16, 16]
  const float* edge_vec = (const float*)d_in[2]; // [E, 3]
  const int* edge_src = (const int*)d_in[3];     // [E]
  const int* edge_dst = (const int*)d_in[4];     // [E]
  float* out = (float*)d_out;

  const int E = in_sizes[3];
  const int n_atoms = in_sizes[0] / IN_CH;

  const size_t y_bytes = (size_t)n_atoms * Y_STRIDE * sizeof(__half);
  if (ws_size >= y_bytes) {
    __half* y = (__half*)d_ws;
    precompute_y<<<n_atoms, 320, 0, stream>>>(x, W, y, out);
    edge_scatter<<<(E + 15) / 16, 256, 0, stream>>>(y, edge_vec, edge_src,
                                                    edge_dst, out, E);
  } else {
    hipMemsetAsync(out, 0, (size_t)out_size * sizeof(float), stream);
    edge_direct<<<(E + 15) / 16, 256, 0, stream>>>(x, W, edge_vec, edge_src,
                                                   edge_dst, out, E);
  }
}